// Round 5
// baseline (518.703 us; speedup 1.0000x reference)
//
#include <hip/hip_runtime.h>
#include <hip/hip_bf16.h>

#define NN 16384
#define DD 128
#define KP1 11
#define NSPLIT 8
#define CBLK 64
#define COLS_PER_SPLIT (NN / NSPLIT)   /* 2048 */
#define NITER (COLS_PER_SPLIT / CBLK)  /* 32 */

typedef __attribute__((ext_vector_type(8))) short bf16x8;
typedef __attribute__((ext_vector_type(4))) float f32x4;
typedef __attribute__((ext_vector_type(16))) float f32x16;
typedef unsigned long long u64;
typedef unsigned int u32;

// ---------------------------------------------------------------------------
// Phase A: proj = feat @ W^T (fp32 exact), row L2 norm, bf16 normalized copy
// ---------------------------------------------------------------------------
__global__ __launch_bounds__(256) void phaseA_kernel(
    const float* __restrict__ feat, const float* __restrict__ W,
    float* __restrict__ proj, __hip_bfloat16* __restrict__ nrmb) {
  __shared__ float Wl[DD][132];
  __shared__ float fl[16][DD];
  const int t = threadIdx.x;
  const int blk = blockIdx.x;     // 16 rows per block

  const f32x4* W4 = (const f32x4*)W;
#pragma unroll
  for (int i = 0; i < 16; ++i) {
    int f4 = t + 256 * i;
    *(f32x4*)&Wl[f4 >> 5][(f4 & 31) * 4] = W4[f4];
  }
  const f32x4* F4 = (const f32x4*)(feat + (size_t)blk * 16 * DD);
#pragma unroll
  for (int i = 0; i < 2; ++i) {
    int f4 = t + 256 * i;
    *(f32x4*)&fl[f4 >> 5][(f4 & 31) * 4] = F4[f4];
  }
  __syncthreads();

  const int w = t >> 6, l = t & 63;
#pragma unroll 1
  for (int q = 0; q < 4; ++q) {
    const int rloc = w * 4 + q;
    const int r = blk * 16 + rloc;
    float a0 = 0.f, a1 = 0.f;
#pragma unroll
    for (int k = 0; k < DD; k += 4) {
      f32x4 fv = *(const f32x4*)&fl[rloc][k];
      f32x4 w0 = *(const f32x4*)&Wl[l][k];
      f32x4 w1 = *(const f32x4*)&Wl[l + 64][k];
      a0 += fv[0] * w0[0] + fv[1] * w0[1] + fv[2] * w0[2] + fv[3] * w0[3];
      a1 += fv[0] * w1[0] + fv[1] * w1[1] + fv[2] * w1[2] + fv[3] * w1[3];
    }
    float n2 = a0 * a0 + a1 * a1;
#pragma unroll
    for (int o = 32; o > 0; o >>= 1) n2 += __shfl_xor(n2, o);
    float invn = 1.0f / fmaxf(sqrtf(n2), 1e-12f);
    proj[(size_t)r * DD + l] = a0;
    proj[(size_t)r * DD + l + 64] = a1;
    nrmb[(size_t)r * DD + l] = __float2bfloat16(a0 * invn);
    nrmb[(size_t)r * DD + l + 64] = __float2bfloat16(a1 * invn);
  }
}

// ---------------------------------------------------------------------------
// Phase B: swapped-operand 32x32x16 MFMA Gram + in-register per-row top-11.
// Each lane owns ONE row (l&31); lanes l and l+32 hold disjoint cand halves.
// Cands LDS-staged (T3 single-barrier dbuf, global_load_lds w=16,
// source pre-swizzled chunk^=(cand&7) to kill ds_read bank conflicts).
// Survivors -> depth-4 register queue -> batched drain into 11-named-u64
// ladder (key = orderable-f32<<32 | (16383-idx), jax tie semantics).
// ---------------------------------------------------------------------------
#define LSTEP(kj) { bool g_ = ck > (kj); u64 t_ = g_ ? ck : (kj); \
                    ck = g_ ? (kj) : ck; (kj) = t_; }
#define LADDER11 { LSTEP(k0) LSTEP(k1) LSTEP(k2) LSTEP(k3) LSTEP(k4) \
                   LSTEP(k5) LSTEP(k6) LSTEP(k7) LSTEP(k8) LSTEP(k9) LSTEP(k10) }

#define PUSHCAND(vv, cglob)                                   \
  if ((vv) >= thrv) {                                         \
    u32 b_ = __float_as_uint(vv);                             \
    u32 fk_ = b_ ^ (u32)(((int)b_ >> 31) | 0x80000000);       \
    u64 ck_ = ((u64)fk_ << 32) | (u32)(16383 - (cglob));      \
    q3 = (cnt == 3) ? ck_ : q3;                               \
    q2 = (cnt == 2) ? ck_ : q2;                               \
    q1 = (cnt == 1) ? ck_ : q1;                               \
    q0 = (cnt == 0) ? ck_ : q0;                               \
    ++cnt;                                                    \
  }

#define DRAINQ                                                               \
  if (__any(cnt > 0)) {                                                      \
    do {                                                                     \
      u64 ck = (cnt == 4) ? q3 : (cnt == 3) ? q2                             \
               : (cnt == 2) ? q1 : (cnt == 1) ? q0 : 0ULL;                   \
      if (cnt > 0) --cnt;                                                    \
      LADDER11                                                               \
    } while (__any(cnt > 0));                                                \
    u32 fk10_ = (u32)(k10 >> 32);                                            \
    thrv = (fk10_ == 0u) ? -3.0e38f                                          \
         : __uint_as_float(fk10_ ^ ((fk10_ & 0x80000000u) ? 0x80000000u      \
                                                          : 0xFFFFFFFFu));   \
  }

__device__ __forceinline__ void gload_lds16(const void* g, void* l) {
  __builtin_amdgcn_global_load_lds(
      (const __attribute__((address_space(1))) unsigned int*)g,
      (__attribute__((address_space(3))) unsigned int*)l, 16, 0, 0);
}

__global__ __launch_bounds__(256, 4) void phaseB_kernel(
    const __hip_bfloat16* __restrict__ nrmb,
    float* __restrict__ tkv, int* __restrict__ tki) {
  __shared__ __hip_bfloat16 cand[2][CBLK * DD];   // 2 x 16 KB
  const int t = threadIdx.x;
  const int w = t >> 6, l = t & 63;
  const int l31 = l & 31, hi = l >> 5;
  const int rb = blockIdx.x >> 3;          // 0..127 row-blocks (128 rows)
  const int cs = blockIdx.x & 7;           // col-split
  const int r0 = rb * 128 + w * 32;        // wave's 32 rows
  const int csbase = cs * COLS_PER_SPLIT;
  const unsigned short* nb = (const unsigned short*)nrmb;

  // B-operand frags: my row (r0+l31), k-chunk kt*16 + hi*8 (8 elems each)
  bf16x8 rowF[8];
#pragma unroll
  for (int kt = 0; kt < 8; ++kt)
    rowF[kt] = *(const bf16x8*)(nb + (size_t)(r0 + l31) * DD + kt * 16 + hi * 8);

  u64 k0 = 0, k1 = 0, k2 = 0, k3 = 0, k4 = 0, k5 = 0,
      k6 = 0, k7 = 0, k8 = 0, k9 = 0, k10 = 0;
  u64 q0 = 0, q1 = 0, q2 = 0, q3 = 0;
  int cnt = 0;
  float thrv = -3.0e38f;

  // stage tile: wave w stages cands [w*16, w*16+16); 4 instrs of 1 KB
#define STAGE(bufidx, itile)                                                  \
  {                                                                           \
    const unsigned short* srcb = nb + (size_t)(csbase + (itile)*CBLK) * DD;   \
    _Pragma("unroll")                                                         \
    for (int j = 0; j < 4; ++j) {                                             \
      int cl = w * 16 + j * 4 + (l >> 4);                                     \
      int ch = (l & 15) ^ (cl & 7);                                           \
      gload_lds16(srcb + (size_t)cl * DD + ch * 8,                            \
                  &cand[bufidx][w * 2048 + j * 512]);                         \
    }                                                                         \
  }

  STAGE(0, 0);
  __syncthreads();   // drains vmcnt -> tile 0 landed (all waves)

  int cur = 0;
  const int swsalt = (l31 & 7);
  for (int it = 0; it < NITER; ++it) {
    if (it + 1 < NITER) STAGE(cur ^ 1, it + 1);

    // MFMA: acc row = my row; cands 0..63 of this tile
    f32x16 a0, a1;
#pragma unroll
    for (int i = 0; i < 16; ++i) { a0[i] = 0.f; a1[i] = 0.f; }
    const char* cb = (const char*)&cand[cur][0];
#pragma unroll
    for (int kt = 0; kt < 8; ++kt) {
      const int chsw = ((kt * 2 + hi) ^ swsalt) << 4;
      bf16x8 c0v = *(const bf16x8*)(cb + l31 * 256 + chsw);
      bf16x8 c1v = *(const bf16x8*)(cb + (32 + l31) * 256 + chsw);
      a0 = __builtin_amdgcn_mfma_f32_32x32x16_bf16(c0v, rowF[kt], a0, 0, 0, 0);
      a1 = __builtin_amdgcn_mfma_f32_32x32x16_bf16(c1v, rowF[kt], a1, 0, 0, 0);
    }

    // scan: C/D mapping: cand_local = (reg&3) + 8*(reg>>2) + 4*hi (+ g*32)
    const int cb0 = csbase + it * CBLK + 4 * hi;
    PUSHCAND(a0[0], cb0 + 0) PUSHCAND(a0[1], cb0 + 1)
    PUSHCAND(a0[2], cb0 + 2) PUSHCAND(a0[3], cb0 + 3)
    DRAINQ
    PUSHCAND(a0[4], cb0 + 8) PUSHCAND(a0[5], cb0 + 9)
    PUSHCAND(a0[6], cb0 + 10) PUSHCAND(a0[7], cb0 + 11)
    DRAINQ
    PUSHCAND(a0[8], cb0 + 16) PUSHCAND(a0[9], cb0 + 17)
    PUSHCAND(a0[10], cb0 + 18) PUSHCAND(a0[11], cb0 + 19)
    DRAINQ
    PUSHCAND(a0[12], cb0 + 24) PUSHCAND(a0[13], cb0 + 25)
    PUSHCAND(a0[14], cb0 + 26) PUSHCAND(a0[15], cb0 + 27)
    DRAINQ
    PUSHCAND(a1[0], cb0 + 32) PUSHCAND(a1[1], cb0 + 33)
    PUSHCAND(a1[2], cb0 + 34) PUSHCAND(a1[3], cb0 + 35)
    DRAINQ
    PUSHCAND(a1[4], cb0 + 40) PUSHCAND(a1[5], cb0 + 41)
    PUSHCAND(a1[6], cb0 + 42) PUSHCAND(a1[7], cb0 + 43)
    DRAINQ
    PUSHCAND(a1[8], cb0 + 48) PUSHCAND(a1[9], cb0 + 49)
    PUSHCAND(a1[10], cb0 + 50) PUSHCAND(a1[11], cb0 + 51)
    DRAINQ
    PUSHCAND(a1[12], cb0 + 56) PUSHCAND(a1[13], cb0 + 57)
    PUSHCAND(a1[14], cb0 + 58) PUSHCAND(a1[15], cb0 + 59)
    DRAINQ

    __syncthreads();  // drains vmcnt (next tile landed) + all reads done
    cur ^= 1;
  }

  // merge lane <-> lane+32 partial ladders (disjoint cand halves, same row)
  {
    long long m0 = __shfl_xor((long long)k0, 32);
    long long m1 = __shfl_xor((long long)k1, 32);
    long long m2 = __shfl_xor((long long)k2, 32);
    long long m3 = __shfl_xor((long long)k3, 32);
    long long m4 = __shfl_xor((long long)k4, 32);
    long long m5 = __shfl_xor((long long)k5, 32);
    long long m6 = __shfl_xor((long long)k6, 32);
    long long m7 = __shfl_xor((long long)k7, 32);
    long long m8 = __shfl_xor((long long)k8, 32);
    long long m9 = __shfl_xor((long long)k9, 32);
    long long m10 = __shfl_xor((long long)k10, 32);
    { u64 ck = (u64)m0; LADDER11 }
    { u64 ck = (u64)m1; LADDER11 }
    { u64 ck = (u64)m2; LADDER11 }
    { u64 ck = (u64)m3; LADDER11 }
    { u64 ck = (u64)m4; LADDER11 }
    { u64 ck = (u64)m5; LADDER11 }
    { u64 ck = (u64)m6; LADDER11 }
    { u64 ck = (u64)m7; LADDER11 }
    { u64 ck = (u64)m8; LADDER11 }
    { u64 ck = (u64)m9; LADDER11 }
    { u64 ck = (u64)m10; LADDER11 }
  }

  if (hi == 0) {
    const int myr = r0 + l31;
    float* ov = tkv + ((size_t)cs * NN + myr) * KP1;
    int* oi = tki + ((size_t)cs * NN + myr) * KP1;
#define OUT1(j, kj)                                                           \
    { u32 fk = (u32)((kj) >> 32);                                             \
      u32 b = fk ^ ((fk & 0x80000000u) ? 0x80000000u : 0xFFFFFFFFu);          \
      ov[j] = __uint_as_float(b); oi[j] = 16383 - (int)((kj) & 0xFFFFFFFFu); }
    OUT1(0, k0) OUT1(1, k1) OUT1(2, k2) OUT1(3, k3) OUT1(4, k4) OUT1(5, k5)
    OUT1(6, k6) OUT1(7, k7) OUT1(8, k8) OUT1(9, k9) OUT1(10, k10)
#undef OUT1
  }
#undef STAGE
}

// ---------------------------------------------------------------------------
// Phase C: merge 8x11 partial top-k per row, softmax (self masked), gather
// one wave per row; 4 rows per 256-thread block. fp32 output.
// ---------------------------------------------------------------------------
__global__ __launch_bounds__(256) void phaseC_kernel(
    const float* __restrict__ proj, const float* __restrict__ feat,
    const float* __restrict__ emb, const float* __restrict__ tkv,
    const int* __restrict__ tki, float* __restrict__ out) {
  const int t = threadIdx.x, w = t >> 6, l = t & 63;
  const int r = blockIdx.x * 4 + w;

  float v0, v1 = -3.0e38f;
  int i0, i1 = 0x7fffffff;
  {
    int j = l, s = j / KP1, k = j - s * KP1;
    v0 = tkv[((size_t)s * NN + r) * KP1 + k];
    i0 = tki[((size_t)s * NN + r) * KP1 + k];
  }
  if (l < 88 - 64) {
    int j = 64 + l, s = j / KP1, k = j - s * KP1;
    v1 = tkv[((size_t)s * NN + r) * KP1 + k];
    i1 = tki[((size_t)s * NN + r) * KP1 + k];
  }

  bool t0 = false, t1 = false;
  float selv[KP1]; int seli[KP1];
#pragma unroll
  for (int s = 0; s < KP1; ++s) {
    float bv = -3.0e38f; int bi = 0x7fffffff;
    if (!t0 && (v0 > bv || (v0 == bv && i0 < bi))) { bv = v0; bi = i0; }
    if (!t1 && (v1 > bv || (v1 == bv && i1 < bi))) { bv = v1; bi = i1; }
#pragma unroll
    for (int o = 32; o > 0; o >>= 1) {
      float ovv = __shfl_xor(bv, o);
      int obi = __shfl_xor(bi, o);
      if (ovv > bv || (ovv == bv && obi < bi)) { bv = ovv; bi = obi; }
    }
    selv[s] = bv; seli[s] = bi;
    if (!t0 && i0 == bi) t0 = true;
    else if (!t1 && i1 == bi) t1 = true;
  }

  float m = -3.0e38f;
#pragma unroll
  for (int s = 0; s < KP1; ++s)
    if (seli[s] != r) m = fmaxf(m, selv[s]);
  float den = 0.f; float wg[KP1];
#pragma unroll
  for (int s = 0; s < KP1; ++s) {
    float e = (seli[s] != r) ? __expf(selv[s] - m) : 0.f;
    wg[s] = e; den += e;
  }
  const float rden = 1.0f / den;

  float p0 = 0.f, p1 = 0.f;
#pragma unroll
  for (int s = 0; s < KP1; ++s) {
    const float* pr = proj + (size_t)seli[s] * DD;
    float ws = wg[s] * rden;
    p0 += ws * pr[l];
    p1 += ws * pr[l + 64];
  }
  out[(size_t)r * DD + l] = feat[(size_t)r * DD + l] + 0.1f * (p0 + emb[l]);
  out[(size_t)r * DD + l + 64] =
      feat[(size_t)r * DD + l + 64] + 0.1f * (p1 + emb[l + 64]);
}

// ---------------------------------------------------------------------------
extern "C" void kernel_launch(void* const* d_in, const int* in_sizes, int n_in,
                              void* d_out, int out_size, void* d_ws, size_t ws_size,
                              hipStream_t stream) {
  (void)in_sizes; (void)n_in; (void)out_size; (void)ws_size;
  const float* feat = (const float*)d_in[0];
  const float* W    = (const float*)d_in[1];
  const float* emb  = (const float*)d_in[2];
  float* out = (float*)d_out;

  char* ws = (char*)d_ws;
  float* proj          = (float*)ws;                                    // 8 MB
  __hip_bfloat16* nrmb = (__hip_bfloat16*)(ws + (size_t)NN * DD * 4);   // 4 MB
  float* tkv = (float*)(ws + (size_t)NN * DD * 6);                      // 5.77 MB
  int*   tki = (int*)(ws + (size_t)NN * DD * 6 +
                      (size_t)NSPLIT * NN * KP1 * 4);                   // 5.77 MB

  phaseA_kernel<<<NN / 16, 256, 0, stream>>>(feat, W, proj, nrmb);
  phaseB_kernel<<<128 * NSPLIT, 256, 0, stream>>>(nrmb, tkv, tki);
  phaseC_kernel<<<NN / 4, 256, 0, stream>>>(proj, feat, emb, tkv, tki, out);
}

// Round 6
// 401.379 us; speedup vs baseline: 1.2923x; 1.2923x over previous
//
#include <hip/hip_runtime.h>
#include <hip/hip_bf16.h>

#define NN 16384
#define DD 128
#define KP1 11
#define NSPLIT 8
#define CBLK 64
#define COLS_PER_SPLIT (NN / NSPLIT)   /* 2048 */
#define NITER (COLS_PER_SPLIT / CBLK)  /* 32 */

typedef __attribute__((ext_vector_type(8))) short bf16x8;
typedef __attribute__((ext_vector_type(4))) float f32x4;
typedef __attribute__((ext_vector_type(16))) float f32x16;
typedef unsigned long long u64;
typedef unsigned int u32;

// ---------------------------------------------------------------------------
// Phase A: proj = feat @ W^T (fp32 exact), row L2 norm, bf16 normalized copy
// ---------------------------------------------------------------------------
__global__ __launch_bounds__(256) void phaseA_kernel(
    const float* __restrict__ feat, const float* __restrict__ W,
    float* __restrict__ proj, __hip_bfloat16* __restrict__ nrmb) {
  __shared__ float Wl[DD][132];
  __shared__ float fl[16][DD];
  const int t = threadIdx.x;
  const int blk = blockIdx.x;     // 16 rows per block

  const f32x4* W4 = (const f32x4*)W;
#pragma unroll
  for (int i = 0; i < 16; ++i) {
    int f4 = t + 256 * i;
    *(f32x4*)&Wl[f4 >> 5][(f4 & 31) * 4] = W4[f4];
  }
  const f32x4* F4 = (const f32x4*)(feat + (size_t)blk * 16 * DD);
#pragma unroll
  for (int i = 0; i < 2; ++i) {
    int f4 = t + 256 * i;
    *(f32x4*)&fl[f4 >> 5][(f4 & 31) * 4] = F4[f4];
  }
  __syncthreads();

  const int w = t >> 6, l = t & 63;
#pragma unroll 1
  for (int q = 0; q < 4; ++q) {
    const int rloc = w * 4 + q;
    const int r = blk * 16 + rloc;
    float a0 = 0.f, a1 = 0.f;
#pragma unroll
    for (int k = 0; k < DD; k += 4) {
      f32x4 fv = *(const f32x4*)&fl[rloc][k];
      f32x4 w0 = *(const f32x4*)&Wl[l][k];
      f32x4 w1 = *(const f32x4*)&Wl[l + 64][k];
      a0 += fv[0] * w0[0] + fv[1] * w0[1] + fv[2] * w0[2] + fv[3] * w0[3];
      a1 += fv[0] * w1[0] + fv[1] * w1[1] + fv[2] * w1[2] + fv[3] * w1[3];
    }
    float n2 = a0 * a0 + a1 * a1;
#pragma unroll
    for (int o = 32; o > 0; o >>= 1) n2 += __shfl_xor(n2, o);
    float invn = 1.0f / fmaxf(sqrtf(n2), 1e-12f);
    proj[(size_t)r * DD + l] = a0;
    proj[(size_t)r * DD + l + 64] = a1;
    nrmb[(size_t)r * DD + l] = __float2bfloat16(a0 * invn);
    nrmb[(size_t)r * DD + l + 64] = __float2bfloat16(a1 * invn);
  }
}

// ---------------------------------------------------------------------------
// Phase B: swapped-operand 32x32x16 MFMA Gram + in-register per-row top-11.
// Lane owns one row (l&31); lanes l / l+32 see disjoint cand halves (merged
// at end by shfl). Cands staged via global_load_lds w=16 (pre-swizzled src,
// T3 single-barrier dbuf). Survivors: f32 threshold -> depth-8 LDS stack,
// drained every 8 candidates (overflow impossible) into 11 named u64 regs.
// Key = orderable-f32<<32 | (16383-idx) == jax (val desc, idx asc) ties.
// ---------------------------------------------------------------------------
#define LSTEP(kj) { bool g_ = ck > (kj); u64 t_ = g_ ? ck : (kj); \
                    ck = g_ ? (kj) : ck; (kj) = t_; }
#define LADDER11 { LSTEP(k0) LSTEP(k1) LSTEP(k2) LSTEP(k3) LSTEP(k4) \
                   LSTEP(k5) LSTEP(k6) LSTEP(k7) LSTEP(k8) LSTEP(k9) LSTEP(k10) }

#define PUSH1(vv, off)                                                  \
  { float v_ = (vv);                                                    \
    if (v_ >= thrv) {                                                   \
      u32 b_ = __float_as_uint(v_);                                     \
      u32 fk_ = b_ ^ (u32)(((int)b_ >> 31) | 0x80000000);               \
      StkL[cnt * 256 + t] = ((u64)fk_ << 32) | (u32)(loid - (off));     \
      ++cnt;                                                            \
    } }

#define DRAIN                                                                \
  {                                                                          \
    while (__any(cnt > 0)) {                                                 \
      u64 ck = 0;                                                            \
      if (cnt > 0) { --cnt; ck = StkL[cnt * 256 + t]; }                      \
      LADDER11                                                               \
    }                                                                        \
    u32 fk10_ = (u32)(k10 >> 32);                                            \
    thrv = (fk10_ == 0u) ? -3.0e38f                                          \
         : __uint_as_float(fk10_ ^ ((fk10_ & 0x80000000u) ? 0x80000000u      \
                                                          : 0xFFFFFFFFu));   \
  }

__device__ __forceinline__ void gload_lds16(const void* g, void* l) {
  __builtin_amdgcn_global_load_lds(
      (const __attribute__((address_space(1))) unsigned int*)g,
      (__attribute__((address_space(3))) unsigned int*)l, 16, 0, 0);
}

__global__ __launch_bounds__(256, 3) void phaseB_kernel(
    const __hip_bfloat16* __restrict__ nrmb,
    float* __restrict__ tkv, int* __restrict__ tki) {
  __shared__ __hip_bfloat16 cand[2][CBLK * DD];   // 2 x 16 KB
  __shared__ u64 StkL[8 * 256];                   // 16 KB -> total 48 KB
  const int t = threadIdx.x;
  const int w = t >> 6, l = t & 63;
  const int l31 = l & 31, hi = l >> 5;
  const int rb = blockIdx.x >> 3;          // 0..127 row-blocks (128 rows)
  const int cs = blockIdx.x & 7;           // col-split
  const int r0 = rb * 128 + w * 32;        // wave's 32 rows
  const int csbase = cs * COLS_PER_SPLIT;
  const unsigned short* nb = (const unsigned short*)nrmb;

  // B-operand frags: my row (r0+l31), k-chunk kt*16 + hi*8
  bf16x8 rowF[8];
#pragma unroll
  for (int kt = 0; kt < 8; ++kt)
    rowF[kt] = *(const bf16x8*)(nb + (size_t)(r0 + l31) * DD + kt * 16 + hi * 8);

  u64 k0 = 0, k1 = 0, k2 = 0, k3 = 0, k4 = 0, k5 = 0,
      k6 = 0, k7 = 0, k8 = 0, k9 = 0, k10 = 0;
  int cnt = 0;
  float thrv = -3.0e38f;

  // wave w stages cands [w*16, w*16+16); source chunk pre-swizzled ^(cl&7)
#define STAGE(bufidx, itile)                                                  \
  {                                                                           \
    const unsigned short* srcb = nb + (size_t)(csbase + (itile)*CBLK) * DD;   \
    _Pragma("unroll")                                                         \
    for (int j = 0; j < 4; ++j) {                                             \
      int cl = w * 16 + j * 4 + (l >> 4);                                     \
      int ch = (l & 15) ^ (cl & 7);                                           \
      gload_lds16(srcb + (size_t)cl * DD + ch * 8,                            \
                  &cand[bufidx][w * 2048 + j * 512]);                         \
    }                                                                         \
  }

  STAGE(0, 0);
  __syncthreads();

  int cur = 0;
  const int swsalt = (l31 & 7);
  for (int it = 0; it < NITER; ++it) {
    if (it + 1 < NITER) STAGE(cur ^ 1, it + 1);
    const char* cb = (const char*)&cand[cur][0];

    // ---- half 0: cands 0..31 of tile ----
    {
      f32x16 a0;
#pragma unroll
      for (int i = 0; i < 16; ++i) a0[i] = 0.f;
#pragma unroll
      for (int kt = 0; kt < 8; ++kt) {
        const int chsw = ((kt * 2 + hi) ^ swsalt) << 4;
        bf16x8 cv = *(const bf16x8*)(cb + l31 * 256 + chsw);
        a0 = __builtin_amdgcn_mfma_f32_32x32x16_bf16(cv, rowF[kt], a0, 0, 0, 0);
      }
      const int loid = 16383 - (csbase + it * CBLK + 4 * hi);
      PUSH1(a0[0], 0)  PUSH1(a0[1], 1)  PUSH1(a0[2], 2)  PUSH1(a0[3], 3)
      PUSH1(a0[4], 8)  PUSH1(a0[5], 9)  PUSH1(a0[6], 10) PUSH1(a0[7], 11)
      DRAIN
      PUSH1(a0[8], 16)  PUSH1(a0[9], 17)  PUSH1(a0[10], 18) PUSH1(a0[11], 19)
      PUSH1(a0[12], 24) PUSH1(a0[13], 25) PUSH1(a0[14], 26) PUSH1(a0[15], 27)
      DRAIN
    }
    // ---- half 1: cands 32..63 of tile ----
    {
      f32x16 a1;
#pragma unroll
      for (int i = 0; i < 16; ++i) a1[i] = 0.f;
#pragma unroll
      for (int kt = 0; kt < 8; ++kt) {
        const int chsw = ((kt * 2 + hi) ^ swsalt) << 4;
        bf16x8 cv = *(const bf16x8*)(cb + (32 + l31) * 256 + chsw);
        a1 = __builtin_amdgcn_mfma_f32_32x32x16_bf16(cv, rowF[kt], a1, 0, 0, 0);
      }
      const int loid = 16383 - (csbase + it * CBLK + 32 + 4 * hi);
      PUSH1(a1[0], 0)  PUSH1(a1[1], 1)  PUSH1(a1[2], 2)  PUSH1(a1[3], 3)
      PUSH1(a1[4], 8)  PUSH1(a1[5], 9)  PUSH1(a1[6], 10) PUSH1(a1[7], 11)
      DRAIN
      PUSH1(a1[8], 16)  PUSH1(a1[9], 17)  PUSH1(a1[10], 18) PUSH1(a1[11], 19)
      PUSH1(a1[12], 24) PUSH1(a1[13], 25) PUSH1(a1[14], 26) PUSH1(a1[15], 27)
      DRAIN
    }

    __syncthreads();  // next tile landed (vmcnt drained) + all reads done
    cur ^= 1;
  }

  // merge lane <-> lane+32 partial ladders (disjoint halves of same row)
  {
    long long m0 = __shfl_xor((long long)k0, 32);
    long long m1 = __shfl_xor((long long)k1, 32);
    long long m2 = __shfl_xor((long long)k2, 32);
    long long m3 = __shfl_xor((long long)k3, 32);
    long long m4 = __shfl_xor((long long)k4, 32);
    long long m5 = __shfl_xor((long long)k5, 32);
    long long m6 = __shfl_xor((long long)k6, 32);
    long long m7 = __shfl_xor((long long)k7, 32);
    long long m8 = __shfl_xor((long long)k8, 32);
    long long m9 = __shfl_xor((long long)k9, 32);
    long long m10 = __shfl_xor((long long)k10, 32);
    { u64 ck = (u64)m0; LADDER11 }
    { u64 ck = (u64)m1; LADDER11 }
    { u64 ck = (u64)m2; LADDER11 }
    { u64 ck = (u64)m3; LADDER11 }
    { u64 ck = (u64)m4; LADDER11 }
    { u64 ck = (u64)m5; LADDER11 }
    { u64 ck = (u64)m6; LADDER11 }
    { u64 ck = (u64)m7; LADDER11 }
    { u64 ck = (u64)m8; LADDER11 }
    { u64 ck = (u64)m9; LADDER11 }
    { u64 ck = (u64)m10; LADDER11 }
  }

  if (hi == 0) {
    const int myr = r0 + l31;
    float* ov = tkv + ((size_t)cs * NN + myr) * KP1;
    int* oi = tki + ((size_t)cs * NN + myr) * KP1;
#define OUT1(j, kj)                                                           \
    { u32 fk = (u32)((kj) >> 32);                                             \
      u32 b = fk ^ ((fk & 0x80000000u) ? 0x80000000u : 0xFFFFFFFFu);          \
      ov[j] = __uint_as_float(b); oi[j] = 16383 - (int)((kj) & 0xFFFFFFFFu); }
    OUT1(0, k0) OUT1(1, k1) OUT1(2, k2) OUT1(3, k3) OUT1(4, k4) OUT1(5, k5)
    OUT1(6, k6) OUT1(7, k7) OUT1(8, k8) OUT1(9, k9) OUT1(10, k10)
#undef OUT1
  }
#undef STAGE
}

// ---------------------------------------------------------------------------
// Phase C: merge 8x11 partial top-k per row, softmax (self masked), gather
// one wave per row; 4 rows per 256-thread block. fp32 output.
// ---------------------------------------------------------------------------
__global__ __launch_bounds__(256) void phaseC_kernel(
    const float* __restrict__ proj, const float* __restrict__ feat,
    const float* __restrict__ emb, const float* __restrict__ tkv,
    const int* __restrict__ tki, float* __restrict__ out) {
  const int t = threadIdx.x, w = t >> 6, l = t & 63;
  const int r = blockIdx.x * 4 + w;

  float v0, v1 = -3.0e38f;
  int i0, i1 = 0x7fffffff;
  {
    int j = l, s = j / KP1, k = j - s * KP1;
    v0 = tkv[((size_t)s * NN + r) * KP1 + k];
    i0 = tki[((size_t)s * NN + r) * KP1 + k];
  }
  if (l < 88 - 64) {
    int j = 64 + l, s = j / KP1, k = j - s * KP1;
    v1 = tkv[((size_t)s * NN + r) * KP1 + k];
    i1 = tki[((size_t)s * NN + r) * KP1 + k];
  }

  bool t0 = false, t1 = false;
  float selv[KP1]; int seli[KP1];
#pragma unroll
  for (int s = 0; s < KP1; ++s) {
    float bv = -3.0e38f; int bi = 0x7fffffff;
    if (!t0 && (v0 > bv || (v0 == bv && i0 < bi))) { bv = v0; bi = i0; }
    if (!t1 && (v1 > bv || (v1 == bv && i1 < bi))) { bv = v1; bi = i1; }
#pragma unroll
    for (int o = 32; o > 0; o >>= 1) {
      float ovv = __shfl_xor(bv, o);
      int obi = __shfl_xor(bi, o);
      if (ovv > bv || (ovv == bv && obi < bi)) { bv = ovv; bi = obi; }
    }
    selv[s] = bv; seli[s] = bi;
    if (!t0 && i0 == bi) t0 = true;
    else if (!t1 && i1 == bi) t1 = true;
  }

  float m = -3.0e38f;
#pragma unroll
  for (int s = 0; s < KP1; ++s)
    if (seli[s] != r) m = fmaxf(m, selv[s]);
  float den = 0.f; float wg[KP1];
#pragma unroll
  for (int s = 0; s < KP1; ++s) {
    float e = (seli[s] != r) ? __expf(selv[s] - m) : 0.f;
    wg[s] = e; den += e;
  }
  const float rden = 1.0f / den;

  float p0 = 0.f, p1 = 0.f;
#pragma unroll
  for (int s = 0; s < KP1; ++s) {
    const float* pr = proj + (size_t)seli[s] * DD;
    float ws = wg[s] * rden;
    p0 += ws * pr[l];
    p1 += ws * pr[l + 64];
  }
  out[(size_t)r * DD + l] = feat[(size_t)r * DD + l] + 0.1f * (p0 + emb[l]);
  out[(size_t)r * DD + l + 64] =
      feat[(size_t)r * DD + l + 64] + 0.1f * (p1 + emb[l + 64]);
}

// ---------------------------------------------------------------------------
extern "C" void kernel_launch(void* const* d_in, const int* in_sizes, int n_in,
                              void* d_out, int out_size, void* d_ws, size_t ws_size,
                              hipStream_t stream) {
  (void)in_sizes; (void)n_in; (void)out_size; (void)ws_size;
  const float* feat = (const float*)d_in[0];
  const float* W    = (const float*)d_in[1];
  const float* emb  = (const float*)d_in[2];
  float* out = (float*)d_out;

  char* ws = (char*)d_ws;
  float* proj          = (float*)ws;                                    // 8 MB
  __hip_bfloat16* nrmb = (__hip_bfloat16*)(ws + (size_t)NN * DD * 4);   // 4 MB
  float* tkv = (float*)(ws + (size_t)NN * DD * 6);                      // 5.77 MB
  int*   tki = (int*)(ws + (size_t)NN * DD * 6 +
                      (size_t)NSPLIT * NN * KP1 * 4);                   // 5.77 MB

  phaseA_kernel<<<NN / 16, 256, 0, stream>>>(feat, W, proj, nrmb);
  phaseB_kernel<<<128 * NSPLIT, 256, 0, stream>>>(nrmb, tkv, tki);
  phaseC_kernel<<<NN / 4, 256, 0, stream>>>(proj, feat, emb, tkv, tki, out);
}

// Round 7
// 245.490 us; speedup vs baseline: 2.1129x; 1.6350x over previous
//
#include <hip/hip_runtime.h>
#include <hip/hip_bf16.h>

#define NN 16384
#define DD 128
#define KP1 11
#define NSPLIT 8
#define CBLK 64
#define COLS_PER_SPLIT (NN / NSPLIT)   /* 2048 */
#define NITER (COLS_PER_SPLIT / CBLK)  /* 32 */

typedef __attribute__((ext_vector_type(8))) short bf16x8;
typedef __attribute__((ext_vector_type(4))) float f32x4;
typedef __attribute__((ext_vector_type(16))) float f32x16;
typedef unsigned long long u64;
typedef unsigned int u32;

// ---------------------------------------------------------------------------
// Phase A: proj = feat @ W^T (fp32 exact), row L2 norm, bf16 normalized copy
// ---------------------------------------------------------------------------
__global__ __launch_bounds__(256) void phaseA_kernel(
    const float* __restrict__ feat, const float* __restrict__ W,
    float* __restrict__ proj, __hip_bfloat16* __restrict__ nrmb) {
  __shared__ float Wl[DD][132];
  __shared__ float fl[16][DD];
  const int t = threadIdx.x;
  const int blk = blockIdx.x;     // 16 rows per block

  const f32x4* W4 = (const f32x4*)W;
#pragma unroll
  for (int i = 0; i < 16; ++i) {
    int f4 = t + 256 * i;
    *(f32x4*)&Wl[f4 >> 5][(f4 & 31) * 4] = W4[f4];
  }
  const f32x4* F4 = (const f32x4*)(feat + (size_t)blk * 16 * DD);
#pragma unroll
  for (int i = 0; i < 2; ++i) {
    int f4 = t + 256 * i;
    *(f32x4*)&fl[f4 >> 5][(f4 & 31) * 4] = F4[f4];
  }
  __syncthreads();

  const int w = t >> 6, l = t & 63;
#pragma unroll 1
  for (int q = 0; q < 4; ++q) {
    const int rloc = w * 4 + q;
    const int r = blk * 16 + rloc;
    float a0 = 0.f, a1 = 0.f;
#pragma unroll
    for (int k = 0; k < DD; k += 4) {
      f32x4 fv = *(const f32x4*)&fl[rloc][k];
      f32x4 w0 = *(const f32x4*)&Wl[l][k];
      f32x4 w1 = *(const f32x4*)&Wl[l + 64][k];
      a0 += fv[0] * w0[0] + fv[1] * w0[1] + fv[2] * w0[2] + fv[3] * w0[3];
      a1 += fv[0] * w1[0] + fv[1] * w1[1] + fv[2] * w1[2] + fv[3] * w1[3];
    }
    float n2 = a0 * a0 + a1 * a1;
#pragma unroll
    for (int o = 32; o > 0; o >>= 1) n2 += __shfl_xor(n2, o);
    float invn = 1.0f / fmaxf(sqrtf(n2), 1e-12f);
    proj[(size_t)r * DD + l] = a0;
    proj[(size_t)r * DD + l + 64] = a1;
    nrmb[(size_t)r * DD + l] = __float2bfloat16(a0 * invn);
    nrmb[(size_t)r * DD + l + 64] = __float2bfloat16(a1 * invn);
  }
}

// ---------------------------------------------------------------------------
// Phase B: swapped-operand 32x32x16 MFMA Gram + in-register per-row top-11.
// Lane owns one row (l&31); lanes l / l+32 see disjoint cand halves (merged
// at end by shfl). Cands staged via global_load_lds w=16 (pre-swizzled src,
// T3 single-barrier dbuf). Survivors: f32 threshold -> depth-8 LDS stack of
// PACKED U32 KEYS: (orderable-f32 & ~2047) | (2047 - local_idx). One u32
// compare == (val desc, idx asc) at 12-mantissa-bit granularity (finer than
// bf16 sim noise). Stack 8 KB -> LDS 40 KB -> 4 blocks/CU, single round.
// ---------------------------------------------------------------------------
#define LSTEP(kj) { bool g_ = ck > (kj); u32 t_ = g_ ? ck : (kj); \
                    ck = g_ ? (kj) : ck; (kj) = t_; }
#define LADDER11 { LSTEP(k0) LSTEP(k1) LSTEP(k2) LSTEP(k3) LSTEP(k4) \
                   LSTEP(k5) LSTEP(k6) LSTEP(k7) LSTEP(k8) LSTEP(k9) LSTEP(k10) }

#define PUSH1(vv, off)                                                  \
  { float v_ = (vv);                                                    \
    if (v_ >= thrv) {                                                   \
      u32 b_ = __float_as_uint(v_);                                     \
      u32 fk_ = b_ ^ (u32)(((int)b_ >> 31) | 0x80000000);               \
      StkL[cnt * 256 + t] = (fk_ & 0xFFFFF800u) | (u32)(loid - (off));  \
      ++cnt;                                                            \
    } }

#define DRAIN                                                                \
  {                                                                          \
    while (__any(cnt > 0)) {                                                 \
      u32 ck = 0;                                                            \
      if (cnt > 0) { --cnt; ck = StkL[cnt * 256 + t]; }                      \
      LADDER11                                                               \
    }                                                                        \
    u32 fkp_ = k10 & 0xFFFFF800u;                                            \
    thrv = (k10 < 2048u) ? -3.0e38f                                          \
         : __uint_as_float(fkp_ ^ ((k10 & 0x80000000u) ? 0x80000000u         \
                                                       : 0xFFFFFFFFu));      \
  }

__device__ __forceinline__ void gload_lds16(const void* g, void* l) {
  __builtin_amdgcn_global_load_lds(
      (const __attribute__((address_space(1))) unsigned int*)g,
      (__attribute__((address_space(3))) unsigned int*)l, 16, 0, 0);
}

__global__ __launch_bounds__(256, 4) void phaseB_kernel(
    const __hip_bfloat16* __restrict__ nrmb,
    float* __restrict__ tkv, int* __restrict__ tki) {
  __shared__ __hip_bfloat16 cand[2][CBLK * DD];   // 2 x 16 KB
  __shared__ u32 StkL[8 * 256];                   // 8 KB -> total 40 KB
  const int t = threadIdx.x;
  const int w = t >> 6, l = t & 63;
  const int l31 = l & 31, hi = l >> 5;
  const int rb = blockIdx.x >> 3;          // 0..127 row-blocks (128 rows)
  const int cs = blockIdx.x & 7;           // col-split
  const int r0 = rb * 128 + w * 32;        // wave's 32 rows
  const int csbase = cs * COLS_PER_SPLIT;
  const unsigned short* nb = (const unsigned short*)nrmb;

  // B-operand frags: my row (r0+l31), k-chunk kt*16 + hi*8
  bf16x8 rowF[8];
#pragma unroll
  for (int kt = 0; kt < 8; ++kt)
    rowF[kt] = *(const bf16x8*)(nb + (size_t)(r0 + l31) * DD + kt * 16 + hi * 8);

  u32 k0 = 0, k1 = 0, k2 = 0, k3 = 0, k4 = 0, k5 = 0,
      k6 = 0, k7 = 0, k8 = 0, k9 = 0, k10 = 0;
  int cnt = 0;
  float thrv = -3.0e38f;

  // wave w stages cands [w*16, w*16+16); source chunk pre-swizzled ^(cl&7)
#define STAGE(bufidx, itile)                                                  \
  {                                                                           \
    const unsigned short* srcb = nb + (size_t)(csbase + (itile)*CBLK) * DD;   \
    _Pragma("unroll")                                                         \
    for (int j = 0; j < 4; ++j) {                                             \
      int cl = w * 16 + j * 4 + (l >> 4);                                     \
      int ch = (l & 15) ^ (cl & 7);                                           \
      gload_lds16(srcb + (size_t)cl * DD + ch * 8,                            \
                  &cand[bufidx][w * 2048 + j * 512]);                         \
    }                                                                         \
  }

  STAGE(0, 0);
  __syncthreads();

  int cur = 0;
  const int swsalt = (l31 & 7);
  for (int it = 0; it < NITER; ++it) {
    if (it + 1 < NITER) STAGE(cur ^ 1, it + 1);
    const char* cb = (const char*)&cand[cur][0];

    // ---- half 0: cands 0..31 of tile ----
    {
      f32x16 a0;
#pragma unroll
      for (int i = 0; i < 16; ++i) a0[i] = 0.f;
#pragma unroll
      for (int kt = 0; kt < 8; ++kt) {
        const int chsw = ((kt * 2 + hi) ^ swsalt) << 4;
        bf16x8 cv = *(const bf16x8*)(cb + l31 * 256 + chsw);
        a0 = __builtin_amdgcn_mfma_f32_32x32x16_bf16(cv, rowF[kt], a0, 0, 0, 0);
      }
      const int loid = 2047 - (it * CBLK + 4 * hi);
      PUSH1(a0[0], 0)  PUSH1(a0[1], 1)  PUSH1(a0[2], 2)  PUSH1(a0[3], 3)
      PUSH1(a0[4], 8)  PUSH1(a0[5], 9)  PUSH1(a0[6], 10) PUSH1(a0[7], 11)
      DRAIN
      PUSH1(a0[8], 16)  PUSH1(a0[9], 17)  PUSH1(a0[10], 18) PUSH1(a0[11], 19)
      PUSH1(a0[12], 24) PUSH1(a0[13], 25) PUSH1(a0[14], 26) PUSH1(a0[15], 27)
      DRAIN
    }
    // ---- half 1: cands 32..63 of tile ----
    {
      f32x16 a1;
#pragma unroll
      for (int i = 0; i < 16; ++i) a1[i] = 0.f;
#pragma unroll
      for (int kt = 0; kt < 8; ++kt) {
        const int chsw = ((kt * 2 + hi) ^ swsalt) << 4;
        bf16x8 cv = *(const bf16x8*)(cb + (32 + l31) * 256 + chsw);
        a1 = __builtin_amdgcn_mfma_f32_32x32x16_bf16(cv, rowF[kt], a1, 0, 0, 0);
      }
      const int loid = 2047 - (it * CBLK + 32 + 4 * hi);
      PUSH1(a1[0], 0)  PUSH1(a1[1], 1)  PUSH1(a1[2], 2)  PUSH1(a1[3], 3)
      PUSH1(a1[4], 8)  PUSH1(a1[5], 9)  PUSH1(a1[6], 10) PUSH1(a1[7], 11)
      DRAIN
      PUSH1(a1[8], 16)  PUSH1(a1[9], 17)  PUSH1(a1[10], 18) PUSH1(a1[11], 19)
      PUSH1(a1[12], 24) PUSH1(a1[13], 25) PUSH1(a1[14], 26) PUSH1(a1[15], 27)
      DRAIN
    }

    __syncthreads();  // next tile landed (vmcnt drained) + all reads done
    cur ^= 1;
  }

  // merge lane <-> lane+32 partial ladders (disjoint halves of same row)
  {
    int m0 = __shfl_xor((int)k0, 32);
    int m1 = __shfl_xor((int)k1, 32);
    int m2 = __shfl_xor((int)k2, 32);
    int m3 = __shfl_xor((int)k3, 32);
    int m4 = __shfl_xor((int)k4, 32);
    int m5 = __shfl_xor((int)k5, 32);
    int m6 = __shfl_xor((int)k6, 32);
    int m7 = __shfl_xor((int)k7, 32);
    int m8 = __shfl_xor((int)k8, 32);
    int m9 = __shfl_xor((int)k9, 32);
    int m10 = __shfl_xor((int)k10, 32);
    { u32 ck = (u32)m0; LADDER11 }
    { u32 ck = (u32)m1; LADDER11 }
    { u32 ck = (u32)m2; LADDER11 }
    { u32 ck = (u32)m3; LADDER11 }
    { u32 ck = (u32)m4; LADDER11 }
    { u32 ck = (u32)m5; LADDER11 }
    { u32 ck = (u32)m6; LADDER11 }
    { u32 ck = (u32)m7; LADDER11 }
    { u32 ck = (u32)m8; LADDER11 }
    { u32 ck = (u32)m9; LADDER11 }
    { u32 ck = (u32)m10; LADDER11 }
  }

  if (hi == 0) {
    const int myr = r0 + l31;
    float* ov = tkv + ((size_t)cs * NN + myr) * KP1;
    int* oi = tki + ((size_t)cs * NN + myr) * KP1;
#define OUT1(j, kj)                                                           \
    { u32 fk = (kj) & 0xFFFFF800u;                                            \
      u32 b = fk ^ ((fk & 0x80000000u) ? 0x80000000u : 0xFFFFFFFFu);          \
      ov[j] = __uint_as_float(b);                                             \
      oi[j] = csbase + 2047 - (int)((kj) & 2047u); }
    OUT1(0, k0) OUT1(1, k1) OUT1(2, k2) OUT1(3, k3) OUT1(4, k4) OUT1(5, k5)
    OUT1(6, k6) OUT1(7, k7) OUT1(8, k8) OUT1(9, k9) OUT1(10, k10)
#undef OUT1
  }
#undef STAGE
}

// ---------------------------------------------------------------------------
// Phase C: merge 8x11 partial top-k per row, softmax (self masked), gather
// one wave per row; 4 rows per 256-thread block. fp32 output.
// ---------------------------------------------------------------------------
__global__ __launch_bounds__(256) void phaseC_kernel(
    const float* __restrict__ proj, const float* __restrict__ feat,
    const float* __restrict__ emb, const float* __restrict__ tkv,
    const int* __restrict__ tki, float* __restrict__ out) {
  const int t = threadIdx.x, w = t >> 6, l = t & 63;
  const int r = blockIdx.x * 4 + w;

  float v0, v1 = -3.0e38f;
  int i0, i1 = 0x7fffffff;
  {
    int j = l, s = j / KP1, k = j - s * KP1;
    v0 = tkv[((size_t)s * NN + r) * KP1 + k];
    i0 = tki[((size_t)s * NN + r) * KP1 + k];
  }
  if (l < 88 - 64) {
    int j = 64 + l, s = j / KP1, k = j - s * KP1;
    v1 = tkv[((size_t)s * NN + r) * KP1 + k];
    i1 = tki[((size_t)s * NN + r) * KP1 + k];
  }

  bool t0 = false, t1 = false;
  float selv[KP1]; int seli[KP1];
#pragma unroll
  for (int s = 0; s < KP1; ++s) {
    float bv = -3.0e38f; int bi = 0x7fffffff;
    if (!t0 && (v0 > bv || (v0 == bv && i0 < bi))) { bv = v0; bi = i0; }
    if (!t1 && (v1 > bv || (v1 == bv && i1 < bi))) { bv = v1; bi = i1; }
#pragma unroll
    for (int o = 32; o > 0; o >>= 1) {
      float ovv = __shfl_xor(bv, o);
      int obi = __shfl_xor(bi, o);
      if (ovv > bv || (ovv == bv && obi < bi)) { bv = ovv; bi = obi; }
    }
    selv[s] = bv; seli[s] = bi;
    if (!t0 && i0 == bi) t0 = true;
    else if (!t1 && i1 == bi) t1 = true;
  }

  float m = -3.0e38f;
#pragma unroll
  for (int s = 0; s < KP1; ++s)
    if (seli[s] != r) m = fmaxf(m, selv[s]);
  float den = 0.f; float wg[KP1];
#pragma unroll
  for (int s = 0; s < KP1; ++s) {
    float e = (seli[s] != r) ? __expf(selv[s] - m) : 0.f;
    wg[s] = e; den += e;
  }
  const float rden = 1.0f / den;

  float p0 = 0.f, p1 = 0.f;
#pragma unroll
  for (int s = 0; s < KP1; ++s) {
    const float* pr = proj + (size_t)seli[s] * DD;
    float ws = wg[s] * rden;
    p0 += ws * pr[l];
    p1 += ws * pr[l + 64];
  }
  out[(size_t)r * DD + l] = feat[(size_t)r * DD + l] + 0.1f * (p0 + emb[l]);
  out[(size_t)r * DD + l + 64] =
      feat[(size_t)r * DD + l + 64] + 0.1f * (p1 + emb[l + 64]);
}

// ---------------------------------------------------------------------------
extern "C" void kernel_launch(void* const* d_in, const int* in_sizes, int n_in,
                              void* d_out, int out_size, void* d_ws, size_t ws_size,
                              hipStream_t stream) {
  (void)in_sizes; (void)n_in; (void)out_size; (void)ws_size;
  const float* feat = (const float*)d_in[0];
  const float* W    = (const float*)d_in[1];
  const float* emb  = (const float*)d_in[2];
  float* out = (float*)d_out;

  char* ws = (char*)d_ws;
  float* proj          = (float*)ws;                                    // 8 MB
  __hip_bfloat16* nrmb = (__hip_bfloat16*)(ws + (size_t)NN * DD * 4);   // 4 MB
  float* tkv = (float*)(ws + (size_t)NN * DD * 6);                      // 5.77 MB
  int*   tki = (int*)(ws + (size_t)NN * DD * 6 +
                      (size_t)NSPLIT * NN * KP1 * 4);                   // 5.77 MB

  phaseA_kernel<<<NN / 16, 256, 0, stream>>>(feat, W, proj, nrmb);
  phaseB_kernel<<<128 * NSPLIT, 256, 0, stream>>>(nrmb, tkv, tki);
  phaseC_kernel<<<NN / 4, 256, 0, stream>>>(proj, feat, emb, tkv, tki, out);
}

// Round 8
// 235.179 us; speedup vs baseline: 2.2056x; 1.0438x over previous
//
#include <hip/hip_runtime.h>
#include <hip/hip_bf16.h>

#define NN 16384
#define DD 128
#define KP1 11
#define NSPLIT 8
#define CBLK 64
#define COLS_PER_SPLIT (NN / NSPLIT)   /* 2048 */
#define NITER (COLS_PER_SPLIT / CBLK)  /* 32 */

typedef __attribute__((ext_vector_type(8))) short bf16x8;
typedef __attribute__((ext_vector_type(4))) float f32x4;
typedef __attribute__((ext_vector_type(16))) float f32x16;
typedef unsigned long long u64;
typedef unsigned int u32;

// ---------------------------------------------------------------------------
// Phase A: proj = feat @ W^T (fp32 exact), row L2 norm, bf16 normalized copy
// ---------------------------------------------------------------------------
__global__ __launch_bounds__(256) void phaseA_kernel(
    const float* __restrict__ feat, const float* __restrict__ W,
    float* __restrict__ proj, __hip_bfloat16* __restrict__ nrmb) {
  __shared__ float Wl[DD][132];
  __shared__ float fl[16][DD];
  const int t = threadIdx.x;
  const int blk = blockIdx.x;     // 16 rows per block

  const f32x4* W4 = (const f32x4*)W;
#pragma unroll
  for (int i = 0; i < 16; ++i) {
    int f4 = t + 256 * i;
    *(f32x4*)&Wl[f4 >> 5][(f4 & 31) * 4] = W4[f4];
  }
  const f32x4* F4 = (const f32x4*)(feat + (size_t)blk * 16 * DD);
#pragma unroll
  for (int i = 0; i < 2; ++i) {
    int f4 = t + 256 * i;
    *(f32x4*)&fl[f4 >> 5][(f4 & 31) * 4] = F4[f4];
  }
  __syncthreads();

  const int w = t >> 6, l = t & 63;
#pragma unroll 1
  for (int q = 0; q < 4; ++q) {
    const int rloc = w * 4 + q;
    const int r = blk * 16 + rloc;
    float a0 = 0.f, a1 = 0.f;
#pragma unroll
    for (int k = 0; k < DD; k += 4) {
      f32x4 fv = *(const f32x4*)&fl[rloc][k];
      f32x4 w0 = *(const f32x4*)&Wl[l][k];
      f32x4 w1 = *(const f32x4*)&Wl[l + 64][k];
      a0 += fv[0] * w0[0] + fv[1] * w0[1] + fv[2] * w0[2] + fv[3] * w0[3];
      a1 += fv[0] * w1[0] + fv[1] * w1[1] + fv[2] * w1[2] + fv[3] * w1[3];
    }
    float n2 = a0 * a0 + a1 * a1;
#pragma unroll
    for (int o = 32; o > 0; o >>= 1) n2 += __shfl_xor(n2, o);
    float invn = 1.0f / fmaxf(sqrtf(n2), 1e-12f);
    proj[(size_t)r * DD + l] = a0;
    proj[(size_t)r * DD + l + 64] = a1;
    nrmb[(size_t)r * DD + l] = __float2bfloat16(a0 * invn);
    nrmb[(size_t)r * DD + l + 64] = __float2bfloat16(a1 * invn);
  }
}

// ---------------------------------------------------------------------------
// Phase B: swapped-operand 32x32x16 MFMA Gram + in-register per-row top-11.
// Keys in +2.0 domain: v+2 is a positive float -> raw bits are monotone ->
// key = (bits(v+2) & ~2047) | (2047 - local_idx). One u32 compare ==
// (val desc, idx asc). Empty ladder (k10=0) => thr = -2 - eps => pass-all.
// thr is shared across the lane pair owning the same row (union 11th >=
// each lane's 11th => max is safe & tighter). Survivors -> depth-8 LDS
// stack, full drain per 8-cand window (overflow impossible).
// ---------------------------------------------------------------------------
#define LSTEP(kj) { bool g_ = ck > (kj); u32 t_ = g_ ? ck : (kj); \
                    ck = g_ ? (kj) : ck; (kj) = t_; }
#define LADDER11 { LSTEP(k0) LSTEP(k1) LSTEP(k2) LSTEP(k3) LSTEP(k4) \
                   LSTEP(k5) LSTEP(k6) LSTEP(k7) LSTEP(k8) LSTEP(k9) LSTEP(k10) }

#define PUSH1(vv, off)                                                  \
  { float v_ = (vv);                                                    \
    if (v_ >= thrm2) {                                                  \
      u32 b_ = __float_as_uint(v_ + 2.0f);                              \
      StkL[cnt * 256 + t] = (b_ & 0xFFFFF800u) | (u32)(loid - (off));   \
      ++cnt;                                                            \
    } }

#define DRAIN                                                                \
  {                                                                          \
    while (__any(cnt > 0)) {                                                 \
      u32 ck = 0;                                                            \
      if (cnt > 0) { --cnt; ck = StkL[cnt * 256 + t]; }                      \
      LADDER11                                                               \
    }                                                                        \
    float th_ = __uint_as_float(k10 & 0xFFFFF800u);                          \
    th_ = fmaxf(th_, __shfl_xor(th_, 32));                                   \
    thrm2 = th_ - 2.0f - 1e-6f;                                              \
  }

__device__ __forceinline__ void gload_lds16(const void* g, void* l) {
  __builtin_amdgcn_global_load_lds(
      (const __attribute__((address_space(1))) unsigned int*)g,
      (__attribute__((address_space(3))) unsigned int*)l, 16, 0, 0);
}

__global__ __launch_bounds__(256, 4) void phaseB_kernel(
    const __hip_bfloat16* __restrict__ nrmb,
    float* __restrict__ tkv, int* __restrict__ tki) {
  __shared__ __hip_bfloat16 cand[2][CBLK * DD];   // 2 x 16 KB
  __shared__ u32 StkL[8 * 256];                   // 8 KB -> total 40 KB
  const int t = threadIdx.x;
  const int w = t >> 6, l = t & 63;
  const int l31 = l & 31, hi = l >> 5;
  const int rb = blockIdx.x >> 3;          // 0..127 row-blocks (128 rows)
  const int cs = blockIdx.x & 7;           // col-split
  const int r0 = rb * 128 + w * 32;        // wave's 32 rows
  const int csbase = cs * COLS_PER_SPLIT;
  const unsigned short* nb = (const unsigned short*)nrmb;

  // B-operand frags: my row (r0+l31), k-chunk kt*16 + hi*8
  bf16x8 rowF[8];
#pragma unroll
  for (int kt = 0; kt < 8; ++kt)
    rowF[kt] = *(const bf16x8*)(nb + (size_t)(r0 + l31) * DD + kt * 16 + hi * 8);

  u32 k0 = 0, k1 = 0, k2 = 0, k3 = 0, k4 = 0, k5 = 0,
      k6 = 0, k7 = 0, k8 = 0, k9 = 0, k10 = 0;
  int cnt = 0;
  float thrm2 = -3.0e38f;

  // wave w stages cands [w*16, w*16+16); source chunk pre-swizzled ^(cl&7)
#define STAGE(bufidx, itile)                                                  \
  {                                                                           \
    const unsigned short* srcb = nb + (size_t)(csbase + (itile)*CBLK) * DD;   \
    _Pragma("unroll")                                                         \
    for (int j = 0; j < 4; ++j) {                                             \
      int cl = w * 16 + j * 4 + (l >> 4);                                     \
      int ch = (l & 15) ^ (cl & 7);                                           \
      gload_lds16(srcb + (size_t)cl * DD + ch * 8,                            \
                  &cand[bufidx][w * 2048 + j * 512]);                         \
    }                                                                         \
  }

  STAGE(0, 0);
  __syncthreads();

  int cur = 0;
  const int swsalt = (l31 & 7);
  for (int it = 0; it < NITER; ++it) {
    if (it + 1 < NITER) STAGE(cur ^ 1, it + 1);
    const char* cb = (const char*)&cand[cur][0];

    // ---- half 0: cands 0..31 of tile ----
    {
      f32x16 a0;
#pragma unroll
      for (int i = 0; i < 16; ++i) a0[i] = 0.f;
#pragma unroll
      for (int kt = 0; kt < 8; ++kt) {
        const int chsw = ((kt * 2 + hi) ^ swsalt) << 4;
        bf16x8 cv = *(const bf16x8*)(cb + l31 * 256 + chsw);
        a0 = __builtin_amdgcn_mfma_f32_32x32x16_bf16(cv, rowF[kt], a0, 0, 0, 0);
      }
      const int loid = 2047 - (it * CBLK + 4 * hi);
      PUSH1(a0[0], 0)  PUSH1(a0[1], 1)  PUSH1(a0[2], 2)  PUSH1(a0[3], 3)
      PUSH1(a0[4], 8)  PUSH1(a0[5], 9)  PUSH1(a0[6], 10) PUSH1(a0[7], 11)
      DRAIN
      PUSH1(a0[8], 16)  PUSH1(a0[9], 17)  PUSH1(a0[10], 18) PUSH1(a0[11], 19)
      PUSH1(a0[12], 24) PUSH1(a0[13], 25) PUSH1(a0[14], 26) PUSH1(a0[15], 27)
      DRAIN
    }
    // ---- half 1: cands 32..63 of tile ----
    {
      f32x16 a1;
#pragma unroll
      for (int i = 0; i < 16; ++i) a1[i] = 0.f;
#pragma unroll
      for (int kt = 0; kt < 8; ++kt) {
        const int chsw = ((kt * 2 + hi) ^ swsalt) << 4;
        bf16x8 cv = *(const bf16x8*)(cb + (32 + l31) * 256 + chsw);
        a1 = __builtin_amdgcn_mfma_f32_32x32x16_bf16(cv, rowF[kt], a1, 0, 0, 0);
      }
      const int loid = 2047 - (it * CBLK + 32 + 4 * hi);
      PUSH1(a1[0], 0)  PUSH1(a1[1], 1)  PUSH1(a1[2], 2)  PUSH1(a1[3], 3)
      PUSH1(a1[4], 8)  PUSH1(a1[5], 9)  PUSH1(a1[6], 10) PUSH1(a1[7], 11)
      DRAIN
      PUSH1(a1[8], 16)  PUSH1(a1[9], 17)  PUSH1(a1[10], 18) PUSH1(a1[11], 19)
      PUSH1(a1[12], 24) PUSH1(a1[13], 25) PUSH1(a1[14], 26) PUSH1(a1[15], 27)
      DRAIN
    }

    __syncthreads();  // next tile landed (vmcnt drained) + all reads done
    cur ^= 1;
  }

  // merge lane <-> lane+32 partial ladders (disjoint halves of same row)
  {
    int m0 = __shfl_xor((int)k0, 32);
    int m1 = __shfl_xor((int)k1, 32);
    int m2 = __shfl_xor((int)k2, 32);
    int m3 = __shfl_xor((int)k3, 32);
    int m4 = __shfl_xor((int)k4, 32);
    int m5 = __shfl_xor((int)k5, 32);
    int m6 = __shfl_xor((int)k6, 32);
    int m7 = __shfl_xor((int)k7, 32);
    int m8 = __shfl_xor((int)k8, 32);
    int m9 = __shfl_xor((int)k9, 32);
    int m10 = __shfl_xor((int)k10, 32);
    { u32 ck = (u32)m0; LADDER11 }
    { u32 ck = (u32)m1; LADDER11 }
    { u32 ck = (u32)m2; LADDER11 }
    { u32 ck = (u32)m3; LADDER11 }
    { u32 ck = (u32)m4; LADDER11 }
    { u32 ck = (u32)m5; LADDER11 }
    { u32 ck = (u32)m6; LADDER11 }
    { u32 ck = (u32)m7; LADDER11 }
    { u32 ck = (u32)m8; LADDER11 }
    { u32 ck = (u32)m9; LADDER11 }
    { u32 ck = (u32)m10; LADDER11 }
  }

  if (hi == 0) {
    const int myr = r0 + l31;
    float* ov = tkv + ((size_t)cs * NN + myr) * KP1;
    int* oi = tki + ((size_t)cs * NN + myr) * KP1;
#define OUT1(j, kj)                                                           \
    { float vq = __uint_as_float((kj) & 0xFFFFF800u) - 2.0f;                  \
      ov[j] = vq;                                                             \
      oi[j] = csbase + 2047 - (int)((kj) & 2047u); }
    OUT1(0, k0) OUT1(1, k1) OUT1(2, k2) OUT1(3, k3) OUT1(4, k4) OUT1(5, k5)
    OUT1(6, k6) OUT1(7, k7) OUT1(8, k8) OUT1(9, k9) OUT1(10, k10)
#undef OUT1
  }
#undef STAGE
}

// ---------------------------------------------------------------------------
// Phase C: merge 8x11 partial top-k per row, softmax (self masked), gather
// one wave per row; 4 rows per 256-thread block. fp32 output.
// ---------------------------------------------------------------------------
__global__ __launch_bounds__(256) void phaseC_kernel(
    const float* __restrict__ proj, const float* __restrict__ feat,
    const float* __restrict__ emb, const float* __restrict__ tkv,
    const int* __restrict__ tki, float* __restrict__ out) {
  const int t = threadIdx.x, w = t >> 6, l = t & 63;
  const int r = blockIdx.x * 4 + w;

  float v0, v1 = -3.0e38f;
  int i0, i1 = 0x7fffffff;
  {
    int j = l, s = j / KP1, k = j - s * KP1;
    v0 = tkv[((size_t)s * NN + r) * KP1 + k];
    i0 = tki[((size_t)s * NN + r) * KP1 + k];
  }
  if (l < 88 - 64) {
    int j = 64 + l, s = j / KP1, k = j - s * KP1;
    v1 = tkv[((size_t)s * NN + r) * KP1 + k];
    i1 = tki[((size_t)s * NN + r) * KP1 + k];
  }

  bool t0 = false, t1 = false;
  float selv[KP1]; int seli[KP1];
#pragma unroll
  for (int s = 0; s < KP1; ++s) {
    float bv = -3.0e38f; int bi = 0x7fffffff;
    if (!t0 && (v0 > bv || (v0 == bv && i0 < bi))) { bv = v0; bi = i0; }
    if (!t1 && (v1 > bv || (v1 == bv && i1 < bi))) { bv = v1; bi = i1; }
#pragma unroll
    for (int o = 32; o > 0; o >>= 1) {
      float ovv = __shfl_xor(bv, o);
      int obi = __shfl_xor(bi, o);
      if (ovv > bv || (ovv == bv && obi < bi)) { bv = ovv; bi = obi; }
    }
    selv[s] = bv; seli[s] = bi;
    if (!t0 && i0 == bi) t0 = true;
    else if (!t1 && i1 == bi) t1 = true;
  }

  float m = -3.0e38f;
#pragma unroll
  for (int s = 0; s < KP1; ++s)
    if (seli[s] != r) m = fmaxf(m, selv[s]);
  float den = 0.f; float wg[KP1];
#pragma unroll
  for (int s = 0; s < KP1; ++s) {
    float e = (seli[s] != r) ? __expf(selv[s] - m) : 0.f;
    wg[s] = e; den += e;
  }
  const float rden = 1.0f / den;

  float p0 = 0.f, p1 = 0.f;
#pragma unroll
  for (int s = 0; s < KP1; ++s) {
    const float* pr = proj + (size_t)seli[s] * DD;
    float ws = wg[s] * rden;
    p0 += ws * pr[l];
    p1 += ws * pr[l + 64];
  }
  out[(size_t)r * DD + l] = feat[(size_t)r * DD + l] + 0.1f * (p0 + emb[l]);
  out[(size_t)r * DD + l + 64] =
      feat[(size_t)r * DD + l + 64] + 0.1f * (p1 + emb[l + 64]);
}

// ---------------------------------------------------------------------------
extern "C" void kernel_launch(void* const* d_in, const int* in_sizes, int n_in,
                              void* d_out, int out_size, void* d_ws, size_t ws_size,
                              hipStream_t stream) {
  (void)in_sizes; (void)n_in; (void)out_size; (void)ws_size;
  const float* feat = (const float*)d_in[0];
  const float* W    = (const float*)d_in[1];
  const float* emb  = (const float*)d_in[2];
  float* out = (float*)d_out;

  char* ws = (char*)d_ws;
  float* proj          = (float*)ws;                                    // 8 MB
  __hip_bfloat16* nrmb = (__hip_bfloat16*)(ws + (size_t)NN * DD * 4);   // 4 MB
  float* tkv = (float*)(ws + (size_t)NN * DD * 6);                      // 5.77 MB
  int*   tki = (int*)(ws + (size_t)NN * DD * 6 +
                      (size_t)NSPLIT * NN * KP1 * 4);                   // 5.77 MB

  phaseA_kernel<<<NN / 16, 256, 0, stream>>>(feat, W, proj, nrmb);
  phaseB_kernel<<<128 * NSPLIT, 256, 0, stream>>>(nrmb, tkv, tki);
  phaseC_kernel<<<NN / 4, 256, 0, stream>>>(proj, feat, emb, tkv, tki, out);
}